// Round 2
// baseline (249.323 us; speedup 1.0000x reference)
//
#include <hip/hip_runtime.h>

constexpr int Bn = 4096;
constexpr int Dn = 256;
constexpr int Sn = 256;

// ---------------------------------------------------------------------------
// Kernel 1: user_item_feature[b,d] = bias[d] + sum_k uf_cat[b,k] * W[d,k]
// 256 blocks x 256 threads, FROWS=16 batch rows per block, thread t owns
// output col d=t. uf is block-uniform -> scalar (s_load) operand; W staged
// LDS in 32-k chunks, loaded once into VGPRs per chunk (32 ds_read serve
// 512 FMAs). Register-staged prefetch of next W chunk overlaps compute.
// ---------------------------------------------------------------------------
constexpr int FROWS = 16;
constexpr int FKCH  = 32;

__global__ __launch_bounds__(256) void feat_kernel(
    const float* __restrict__ uf, const float* __restrict__ priv,
    const float* __restrict__ W,  const float* __restrict__ bias,
    float* __restrict__ fout) {
  __shared__ float w_s[Dn][FKCH + 1];   // +1 pad: bank = (d+kk)%32, conflict-free
  const int t  = threadIdx.x;
  const int b0 = blockIdx.x * FROWS;

  float acc[FROWS];
  const float bd = bias[t];
#pragma unroll
  for (int r = 0; r < FROWS; ++r) acc[r] = bd;

  float treg[FKCH];
  // stage chunk 0
#pragma unroll
  for (int p = 0; p < FKCH; ++p) {
    const int j = t + p * 256, d = j >> 5, kk = j & 31;
    treg[p] = W[d * 513 + kk];
  }
#pragma unroll
  for (int p = 0; p < FKCH; ++p) {
    const int j = t + p * 256, d = j >> 5, kk = j & 31;
    w_s[d][kk] = treg[p];
  }
  __syncthreads();

  for (int c = 0; c < 16; ++c) {
    float wreg[FKCH];
#pragma unroll
    for (int kk = 0; kk < FKCH; ++kk) wreg[kk] = w_s[t][kk];

    if (c < 15) {
      const int k0n = (c + 1) * FKCH;
#pragma unroll
      for (int p = 0; p < FKCH; ++p) {
        const int j = t + p * 256, d = j >> 5, kk = j & 31;
        treg[p] = W[d * 513 + k0n + kk];
      }
    }

    const int k0 = c * FKCH;
#pragma unroll
    for (int kk = 0; kk < FKCH; ++kk) {
#pragma unroll
      for (int r = 0; r < FROWS; ++r) {
        // uf index is block-uniform -> scalar load, FMA uses SGPR operand
        acc[r] = fmaf(uf[(size_t)(b0 + r) * 512 + k0 + kk], wreg[kk], acc[r]);
      }
    }
    __syncthreads();
    if (c < 15) {
#pragma unroll
      for (int p = 0; p < FKCH; ++p) {
        const int j = t + p * 256, d = j >> 5, kk = j & 31;
        w_s[d][kk] = treg[p];
      }
    }
    __syncthreads();
  }

  // k = 512 remainder: privacy column
  const float w512 = W[t * 513 + 512];
#pragma unroll
  for (int r = 0; r < FROWS; ++r) acc[r] = fmaf(priv[b0 + r], w512, acc[r]);

#pragma unroll
  for (int r = 0; r < FROWS; ++r) fout[(size_t)(b0 + r) * Dn + t] = acc[r];
}

// ---------------------------------------------------------------------------
// Batched butterfly fold: given a (partials of value A, lanes where bit m of
// lane id is 0 keep A-family) and b (value B), returns merged partials with
// each family's reduction problem halved. 63 folds reduce 64 values so that
// lane l ends holding the full sum of value l.
// ---------------------------------------------------------------------------
__device__ __forceinline__ float fold(float a, float b, int m, int lane) {
  const float keep = (lane & m) ? b : a;
  const float send = (lane & m) ? a : b;
  return keep + __shfl_xor(send, m, 64);
}

// ---------------------------------------------------------------------------
// Kernel 2: scores -> softmax -> weighted item index + weighted feature.
// 4096 blocks x 256 threads (4 waves). Wave w owns s in [w*64, w*64+64).
// 8 gathers in flight per wave; batched fold reduction (no serial shuffle
// chains). Second einsum over ballot-compacted s with p >= 1e-7.
// ---------------------------------------------------------------------------
__global__ __launch_bounds__(256) void main_kernel(
    const int* __restrict__ need_replace,
    const int* __restrict__ user_sample_items,
    const float* __restrict__ all_items,
    float* __restrict__ out_items,   // d_out + 0, Bn floats
    float* __restrict__ feat_io,     // d_out + Bn: f in, feature out
    float* __restrict__ out_scalars) // d_out + Bn + Bn*Dn, 2 floats
{
  __shared__ __align__(16) float f_s[Dn];
  __shared__ int   items_s[Sn];
  __shared__ float red_s[8];
  __shared__ int   sel_idx[Sn];
  __shared__ float sel_p[Sn];
  __shared__ int   warp_cnt[4];

  const int b    = blockIdx.x;
  const int t    = threadIdx.x;
  const int lane = t & 63;
  const int w    = t >> 6;

  const int uid = need_replace[b * 2];
  items_s[t] = user_sample_items[(size_t)uid * Sn + t];
  f_s[t]     = feat_io[(size_t)b * Dn + t];
  __syncthreads();

  const float4 fr  = *(const float4*)&f_s[lane * 4];
  const int    base = w * 64;

  // ---- pass 1: 64 dots per wave, 8 loads in flight, batched fold reduce ----
  float4 e[8];
#pragma unroll
  for (int j = 0; j < 8; ++j)
    e[j] = *(const float4*)&all_items[(size_t)items_s[base + 8 * j] * Dn + lane * 4];

  float grp[8];
#pragma unroll
  for (int c = 0; c < 8; ++c) {
    float p[8];
#pragma unroll
    for (int j = 0; j < 8; ++j) {
      const float4 ev = e[j];
      p[j] = fmaf(fr.x, ev.x, fmaf(fr.y, ev.y, fmaf(fr.z, ev.z, fr.w * ev.w)));
      if (c < 7)
        e[j] = *(const float4*)&all_items[(size_t)items_s[base + (c + 1) + 8 * j] * Dn + lane * 4];
    }
    // in-group folds: pair deltas 32, 16, 8 (j maps to s = c + 8*j)
    const float q0 = fold(p[0], p[4], 32, lane);
    const float q1 = fold(p[1], p[5], 32, lane);
    const float q2 = fold(p[2], p[6], 32, lane);
    const float q3 = fold(p[3], p[7], 32, lane);
    const float r0 = fold(q0, q2, 16, lane);
    const float r1 = fold(q1, q3, 16, lane);
    grp[c] = fold(r0, r1, 8, lane);
  }
  // cross-group folds: deltas 4, 2, 1
  const float s0 = fold(grp[0], grp[4], 4, lane);
  const float s1 = fold(grp[1], grp[5], 4, lane);
  const float s2 = fold(grp[2], grp[6], 4, lane);
  const float s3 = fold(grp[3], grp[7], 4, lane);
  const float t0 = fold(s0, s2, 2, lane);
  const float t1 = fold(s1, s3, 2, lane);
  const float v  = fold(t0, t1, 1, lane);  // lane l holds score for s = base+l = t

  // ---- softmax over S ----
  float m = v;
#pragma unroll
  for (int off = 32; off; off >>= 1) m = fmaxf(m, __shfl_xor(m, off, 64));
  if (lane == 0) red_s[w] = m;
  __syncthreads();
  m = fmaxf(fmaxf(red_s[0], red_s[1]), fmaxf(red_s[2], red_s[3]));

  const float e0 = expf(v - m);
  float ssum = e0;
#pragma unroll
  for (int off = 32; off; off >>= 1) ssum += __shfl_xor(ssum, off, 64);
  if (lane == 0) red_s[4 + w] = ssum;
  __syncthreads();
  const float tot = red_s[4] + red_s[5] + red_s[6] + red_s[7];
  const float p = e0 / tot;

  // ---- weighted item index (exact, all s) ----
  float ri = p * (float)items_s[t];
#pragma unroll
  for (int off = 32; off; off >>= 1) ri += __shfl_xor(ri, off, 64);
  if (lane == 0) red_s[w] = ri;  // after sync2; m-reads of red_s[0..3] done

  // ---- deterministic compaction of significant p ----
  const bool flag = (p >= 1e-7f);
  const unsigned long long mask = __ballot(flag);
  const int wc     = __popcll(mask);
  const int prefix = __popcll(mask & ((1ull << lane) - 1ull));
  if (lane == 0) warp_cnt[w] = wc;
  __syncthreads();

  if (t == 0) {
    const float tot_ri = red_s[0] + red_s[1] + red_s[2] + red_s[3];
    out_items[b] = (float)(int)tot_ri;  // astype(int32) truncation
  }
  int off0 = 0;
  for (int i = 0; i < w; ++i) off0 += warp_cnt[i];
  const int nsel = warp_cnt[0] + warp_cnt[1] + warp_cnt[2] + warp_cnt[3];
  if (flag) {
    sel_idx[off0 + prefix] = items_s[t];
    sel_p[off0 + prefix]   = p;
  }
  __syncthreads();

  // ---- pass 2: weighted feature over compacted s ----
  float acc = 0.f;
  for (int i = 0; i < nsel; ++i) {
    acc += sel_p[i] * all_items[(size_t)sel_idx[i] * Dn + t];
  }
  feat_io[(size_t)b * Dn + t] = acc;

  if (b == 0 && t < 2) out_scalars[t] = 0.f;
}

extern "C" void kernel_launch(void* const* d_in, const int* in_sizes, int n_in,
                              void* d_out, int out_size, void* d_ws, size_t ws_size,
                              hipStream_t stream) {
  const int*   need_replace      = (const int*)d_in[0];
  const float* union_feature     = (const float*)d_in[1];
  const float* all_items         = (const float*)d_in[2];
  const float* privacy_settings  = (const float*)d_in[3];
  const int*   user_sample_items = (const int*)d_in[4];
  const float* W                 = (const float*)d_in[5];
  const float* bias              = (const float*)d_in[6];

  float* out       = (float*)d_out;
  float* out_items = out;                          // Bn
  float* feat_io   = out + Bn;                     // Bn*Dn (f in, feature out)
  float* out_scal  = out + Bn + (size_t)Bn * Dn;   // 2 scalars

  feat_kernel<<<Bn / FROWS, 256, 0, stream>>>(union_feature, privacy_settings,
                                              W, bias, feat_io);
  main_kernel<<<Bn, 256, 0, stream>>>(need_replace, user_sample_items,
                                      all_items, out_items, feat_io, out_scal);
}